// Round 2
// baseline (336.391 us; speedup 1.0000x reference)
//
#include <hip/hip_runtime.h>
#include <math.h>

#define T_LR 20
#define T_HR 30
#define CCH  4
#define H0   256
#define W0   256
#define HH   512
#define WW   512
#define ABOVE 10000

// ws layout (float/int slots):
#define WS_RATE  0    // 30 floats
#define WS_FIDX  64   // 20 ints
#define WS_SIDX  96   // 20 ints
#define WS_ALPHA 128  // 20 floats
#define WS_BETA  160  // 20 floats
#define WS_VALID 192  // 20 ints

// ---------------- Phase A1: per-HR-frame mask rate ----------------
// hr_mask arrives as int32 (0/1) per element.
__global__ void rate_kernel(const int* __restrict__ hr_mask,
                            float* __restrict__ ws) {
    int j = blockIdx.x;
    const uint4* p = (const uint4*)(hr_mask + (size_t)j * HH * WW);
    const int n4 = HH * WW / 4;  // 65536 uint4 (4 ints each) per frame
    int sum = 0;
    for (int e = threadIdx.x; e < n4; e += blockDim.x) {
        uint4 v = p[e];
        sum += (int)(v.x + v.y + v.z + v.w);   // each element is 0 or 1
    }
    for (int o = 32; o; o >>= 1) sum += __shfl_down(sum, o);
    __shared__ int ssum[4];
    if ((threadIdx.x & 63) == 0) ssum[threadIdx.x >> 6] = sum;
    __syncthreads();
    if (threadIdx.x == 0) {
        int t = ssum[0] + ssum[1] + ssum[2] + ssum[3];
        ws[WS_RATE + j] = (float)t / (float)(HH * WW);
    }
}

// ---------------- Phase A2: first/second frame selection ----------------
__global__ void select_kernel(const int* __restrict__ lr_doy,
                              const int* __restrict__ hr_doy,
                              float* __restrict__ ws) {
    int i = threadIdx.x;
    if (i >= T_LR) return;
    const float* rate = ws + WS_RATE;
    int doy = lr_doy[i];

    int fmin = ABOVE, fidx = 0;
    for (int j = 0; j < T_HR; j++) {
        int d = doy - hr_doy[j];
        if (d < 0) d = ABOVE;
        if (rate[j] > 0.5f) d = ABOVE;
        if (d < fmin) { fmin = d; fidx = j; }   // first-occurrence argmin
    }
    int smin = ABOVE, sidx = 0;
    for (int j = 0; j < T_HR; j++) {
        int d = doy - hr_doy[j];
        if (d < 0) d = ABOVE;
        if (rate[j] > 0.5f) d = ABOVE;
        if (j == fidx) d = ABOVE;
        if (d < smin) { smin = d; sidx = j; }
    }
    int valid = (fmin < ABOVE) && (smin < ABOVE);
    float fv = (float)hr_doy[fidx], sv = (float)hr_doy[sidx];
    float denom = sv - fv;
    float alpha = (sv - (float)doy) / denom;   // weight on g1
    float beta  = ((float)doy - fv) / denom;   // weight on g2

    int* wsi = (int*)ws;
    wsi[WS_FIDX + i] = fidx;
    wsi[WS_SIDX + i] = sidx;
    ws[WS_ALPHA + i] = alpha;
    ws[WS_BETA + i]  = beta;
    wsi[WS_VALID + i] = valid;
}

// ---------------- Phase B: fused main kernel ----------------
#define TX 32
#define TY 32

__launch_bounds__(256)
__global__ void fuse_kernel(const float* __restrict__ lr_data,
                            const float* __restrict__ hr_data,
                            const int* __restrict__ lr_mask,
                            const int* __restrict__ hr_mask,
                            const float* __restrict__ ws,
                            float* __restrict__ out,
                            float wc, float we, float wk) {
    const int i  = blockIdx.z;
    const int x0 = blockIdx.x * TX;
    const int y0 = blockIdx.y * TY;

    const int* wsi = (const int*)ws;
    const int f      = wsi[WS_FIDX + i];
    const int s      = wsi[WS_SIDX + i];
    const float alpha = ws[WS_ALPHA + i];
    const float beta  = ws[WS_BETA + i];
    const int valid  = wsi[WS_VALID + i];

    __shared__ float sh[2][CCH][34][34];   // g1/g2 halo tiles
    __shared__ float shl[CCH][18][18];     // lr tile (clamped)

    const float* gbase[2] = { hr_data + (size_t)f * CCH * HH * WW,
                              hr_data + (size_t)s * CCH * HH * WW };

    for (int img = 0; img < 2; img++) {
        for (int ch = 0; ch < CCH; ch++) {
            const float* gp = gbase[img] + (size_t)ch * HH * WW;
            for (int e = threadIdx.x; e < 34 * 34; e += 256) {
                int r = e / 34, cc = e - r * 34;
                int gy = y0 - 1 + r, gx = x0 - 1 + cc;
                float v = 0.f;                         // conv 'SAME' zero-pad
                if (gy >= 0 && gy < HH && gx >= 0 && gx < WW)
                    v = gp[(size_t)gy * WW + gx];
                sh[img][ch][r][cc] = v;
            }
        }
    }
    const int ly0 = (y0 >> 1) - 1, lx0 = (x0 >> 1) - 1;
    for (int ch = 0; ch < CCH; ch++) {
        const float* lp = lr_data + ((size_t)i * CCH + ch) * H0 * W0;
        for (int e = threadIdx.x; e < 18 * 18; e += 256) {
            int r = e / 18, cc = e - r * 18;
            int gy = min(max(ly0 + r, 0), H0 - 1);     // bilinear clamp-to-edge
            int gx = min(max(lx0 + cc, 0), W0 - 1);
            shl[ch][r][cc] = lp[(size_t)gy * W0 + gx];
        }
    }
    __syncthreads();

    const size_t outM  = (size_t)T_LR * CCH * HH * WW;          // final_mask offset
    const size_t outLU = outM + (size_t)T_LR * HH * WW;         // lr_up offset

    for (int p = threadIdx.x; p < TX * TY; p += 256) {
        int ty = p >> 5, tx = p & 31;
        int y = y0 + ty, x = x0 + tx;

        // ---- final_mask (int32 0/1 inputs) ----
        int m = lr_mask[((size_t)i * H0 + (y >> 1)) * W0 + (x >> 1)];
        m |= (int)(!valid);
        m |= hr_mask[((size_t)f * HH + y) * WW + x];
        m |= hr_mask[((size_t)s * HH + y) * WW + x];
        out[outM + ((size_t)i * HH + y) * WW + x] = m ? 1.f : 0.f;

        // ---- bilinear tap indices (local LDS coords) ----
        int jy = y >> 1, jx = x >> 1;
        int cyl = jy - ly0;
        int nyl = min(max(jy + ((y & 1) ? 1 : -1), 0), H0 - 1) - ly0;
        int cxl = jx - lx0;
        int nxl = min(max(jx + ((x & 1) ? 1 : -1), 0), W0 - 1) - lx0;

        for (int ch = 0; ch < CCH; ch++) {
            float a00 = shl[ch][cyl][cxl], a01 = shl[ch][cyl][nxl];
            float a10 = shl[ch][nyl][cxl], a11 = shl[ch][nyl][nxl];
            float lu = 0.75f * (0.75f * a00 + 0.25f * a01)
                     + 0.25f * (0.75f * a10 + 0.25f * a11);

            float hp[2];
            #pragma unroll
            for (int img = 0; img < 2; img++) {
                const float (*t)[34] = sh[img][ch];
                int r = ty + 1, c2 = tx + 1;
                float center = t[r][c2];
                float low =
                    wk * (t[r-1][c2-1] + t[r-1][c2+1] + t[r+1][c2-1] + t[r+1][c2+1]) +
                    we * (t[r-1][c2]   + t[r][c2-1]   + t[r][c2+1]   + t[r+1][c2]) +
                    wc * center;
                hp[img] = center - low;
            }
            float hpf = alpha * hp[0] + beta * hp[1];

            size_t oidx = (((size_t)i * CCH + ch) * HH + y) * WW + x;
            out[oidx]         = lu + hpf;   // final_hr
            out[outLU + oidx] = lu;         // lr_up
        }
    }
}

extern "C" void kernel_launch(void* const* d_in, const int* in_sizes, int n_in,
                              void* d_out, int out_size, void* d_ws, size_t ws_size,
                              hipStream_t stream) {
    const float* lr_data = (const float*)d_in[0];
    const float* hr_data = (const float*)d_in[1];
    const int* lr_doy    = (const int*)d_in[2];
    const int* hr_doy    = (const int*)d_in[3];
    const int* lr_mask   = (const int*)d_in[4];
    const int* hr_mask   = (const int*)d_in[5];
    float* out = (float*)d_out;
    float* ws  = (float*)d_ws;

    // PSF weights, double precision to match numpy then cast to f32
    double sigma = sqrt(-2.0 * log(0.4)) / M_PI;
    double e1 = exp(-1.0 / (2.0 * sigma * sigma));
    double e2 = exp(-2.0 / (2.0 * sigma * sigma));
    double ssum = 1.0 + 4.0 * e1 + 4.0 * e2;
    float wc = (float)(1.0 / ssum);
    float we = (float)(e1 / ssum);
    float wk = (float)(e2 / ssum);

    rate_kernel<<<T_HR, 256, 0, stream>>>(hr_mask, ws);
    select_kernel<<<1, 64, 0, stream>>>(lr_doy, hr_doy, ws);

    dim3 grid(WW / TX, HH / TY, T_LR);
    fuse_kernel<<<grid, 256, 0, stream>>>(lr_data, hr_data, lr_mask, hr_mask,
                                          ws, out, wc, we, wk);
}

// Round 3
// 137.800 us; speedup vs baseline: 2.4411x; 2.4411x over previous
//
#include <hip/hip_runtime.h>
#include <math.h>

#define T_LR 20
#define T_HR 30
#define CCH  4
#define H0   256
#define W0   256
#define HH   512
#define WW   512
#define ABOVE 10000

// ws layout (32-bit slots):
#define WS_FIDX  64   // 20 ints
#define WS_SIDX  96   // 20 ints
#define WS_ALPHA 128  // 20 floats
#define WS_BETA  160  // 20 floats
#define WS_VALID 192  // 20 ints
#define WS_CNT   224  // 30 ints (atomic counters)

// ---------------- Phase A0: zero the atomic counters ----------------
__global__ void zero_kernel(int* __restrict__ wsi) {
    if (threadIdx.x < T_HR) wsi[WS_CNT + threadIdx.x] = 0;
}

// ---------------- Phase A1: per-HR-frame mask count (parallel) ----------------
// hr_mask arrives as int32 (0/1) per element. 8 slices per frame.
__global__ void rate_kernel(const int* __restrict__ hr_mask,
                            int* __restrict__ wsi) {
    int j = blockIdx.x >> 3;          // frame
    int slice = blockIdx.x & 7;       // 1/8 of frame
    const int elems = HH * WW / 8;    // 32768 ints per slice
    const uint4* p = (const uint4*)(hr_mask + (size_t)j * HH * WW + (size_t)slice * elems);
    int sum = 0;
    for (int e = threadIdx.x; e < elems / 4; e += blockDim.x) {
        uint4 v = p[e];
        sum += (int)(v.x + v.y + v.z + v.w);
    }
    for (int o = 32; o; o >>= 1) sum += __shfl_down(sum, o);
    __shared__ int ssum[4];
    if ((threadIdx.x & 63) == 0) ssum[threadIdx.x >> 6] = sum;
    __syncthreads();
    if (threadIdx.x == 0)
        atomicAdd(&wsi[WS_CNT + j], ssum[0] + ssum[1] + ssum[2] + ssum[3]);
}

// ---------------- Phase A2: first/second frame selection ----------------
__global__ void select_kernel(const int* __restrict__ lr_doy,
                              const int* __restrict__ hr_doy,
                              float* __restrict__ ws) {
    int i = threadIdx.x;
    if (i >= T_LR) return;
    const int* wsi_c = (const int*)ws;
    int doy = lr_doy[i];

    int fmin = ABOVE, fidx = 0;
    for (int j = 0; j < T_HR; j++) {
        int d = doy - hr_doy[j];
        if (d < 0) d = ABOVE;
        float rate = (float)wsi_c[WS_CNT + j] / (float)(HH * WW);
        if (rate > 0.5f) d = ABOVE;
        if (d < fmin) { fmin = d; fidx = j; }   // first-occurrence argmin
    }
    int smin = ABOVE, sidx = 0;
    for (int j = 0; j < T_HR; j++) {
        int d = doy - hr_doy[j];
        if (d < 0) d = ABOVE;
        float rate = (float)wsi_c[WS_CNT + j] / (float)(HH * WW);
        if (rate > 0.5f) d = ABOVE;
        if (j == fidx) d = ABOVE;
        if (d < smin) { smin = d; sidx = j; }
    }
    int valid = (fmin < ABOVE) && (smin < ABOVE);
    float fv = (float)hr_doy[fidx], sv = (float)hr_doy[sidx];
    float denom = sv - fv;

    int* wsi = (int*)ws;
    wsi[WS_FIDX + i] = fidx;
    wsi[WS_SIDX + i] = sidx;
    ws[WS_ALPHA + i] = (sv - (float)doy) / denom;   // weight on g1
    ws[WS_BETA + i]  = ((float)doy - fv) / denom;   // weight on g2
    wsi[WS_VALID + i] = valid;
}

// ---------------- Phase B: fused main kernel (one channel per block) ----------------
// grid (16,16,80): z = i*4 + ch. Each thread: 1x4 output strip.
__launch_bounds__(256)
__global__ void fuse_kernel(const float* __restrict__ lr_data,
                            const float* __restrict__ hr_data,
                            const int* __restrict__ lr_mask,
                            const int* __restrict__ hr_mask,
                            const float* __restrict__ ws,
                            float* __restrict__ out,
                            float wc, float we, float wk) {
    const int i  = blockIdx.z >> 2;
    const int ch = blockIdx.z & 3;
    const int x0 = blockIdx.x * 32;
    const int y0 = blockIdx.y * 32;
    const int tid = threadIdx.x;

    const int* wsi = (const int*)ws;
    const int f       = wsi[WS_FIDX + i];
    const int s       = wsi[WS_SIDX + i];
    const float alpha = ws[WS_ALPHA + i];
    const float beta  = ws[WS_BETA + i];
    const int valid   = wsi[WS_VALID + i];

    __shared__ float sh[2][34][40];   // HR halo tiles (zero-padded), cols start at x0-4
    __shared__ float shl[18][24];     // LR tile (clamped), cols start at x0/2-4

    const float* g0 = hr_data + ((size_t)f * CCH + ch) * HH * WW;
    const float* g1 = hr_data + ((size_t)s * CCH + ch) * HH * WW;

    // HR staging: 2 imgs x 34 rows x 10 float4
    for (int e = tid; e < 2 * 340; e += 256) {
        int img = e >= 340;
        int e2 = e - img * 340;
        int r = e2 / 10, c4 = e2 - r * 10;
        int gy = y0 - 1 + r;
        int gx0 = x0 - 4 + c4 * 4;
        float4 v = make_float4(0.f, 0.f, 0.f, 0.f);
        if (gy >= 0 && gy < HH && gx0 >= 0 && gx0 < WW)   // gx0 mult of 4 -> whole f4 valid
            v = *(const float4*)((img ? g1 : g0) + (size_t)gy * WW + gx0);
        *(float4*)&sh[img][r][c4 * 4] = v;
    }

    // LR staging: 18 rows x 6 float4, clamp-to-edge applied here
    const int ly0 = (y0 >> 1) - 1, lx0c = (x0 >> 1) - 4;
    const float* lp = lr_data + ((size_t)i * CCH + ch) * H0 * W0;
    if (tid < 18 * 6) {
        int r = tid / 6, c4 = tid - r * 6;
        int gy = min(max(ly0 + r, 0), H0 - 1);
        int gx0 = lx0c + c4 * 4;
        float4 v;
        if (gx0 >= 0 && gx0 + 3 < W0) {
            v = *(const float4*)(lp + (size_t)gy * W0 + gx0);
        } else {
            v.x = lp[(size_t)gy * W0 + min(max(gx0 + 0, 0), W0 - 1)];
            v.y = lp[(size_t)gy * W0 + min(max(gx0 + 1, 0), W0 - 1)];
            v.z = lp[(size_t)gy * W0 + min(max(gx0 + 2, 0), W0 - 1)];
            v.w = lp[(size_t)gy * W0 + min(max(gx0 + 3, 0), W0 - 1)];
        }
        *(float4*)&shl[r][c4 * 4] = v;
    }
    __syncthreads();

    const int ty = tid >> 3, tx4 = tid & 7;
    const int y = y0 + ty, x = x0 + tx4 * 4;
    const int c = tx4 * 4 + 4;        // HR LDS col of x

    // ---- HPF for both images, 4 outputs each ----
    float hp[2][4];
    #pragma unroll
    for (int img = 0; img < 2; img++) {
        float win[3][6];
        #pragma unroll
        for (int rr = 0; rr < 3; rr++) {
            const float* row = sh[img][ty + rr];
            float4 v = *(const float4*)&row[c];
            win[rr][0] = row[c - 1];
            win[rr][1] = v.x; win[rr][2] = v.y; win[rr][3] = v.z; win[rr][4] = v.w;
            win[rr][5] = row[c + 4];
        }
        #pragma unroll
        for (int k = 0; k < 4; k++) {
            float center = win[1][k + 1];
            float low =
                wk * (win[0][k] + win[0][k + 2] + win[2][k] + win[2][k + 2]) +
                we * (win[0][k + 1] + win[2][k + 1] + win[1][k] + win[1][k + 2]) +
                wc * center;
            hp[img][k] = center - low;
        }
    }

    // ---- bilinear upsample (clamping folded into staging) ----
    const int jy = y >> 1;
    const int lr_c = jy - ly0;                           // 1..16
    const int lr_n = jy + ((y & 1) ? 1 : -1) - ly0;      // 0..17, no clamp needed
    const int c0 = tx4 * 2 + 4;                          // LDS col of gjx0 = x>>1

    float ma = 0.75f * shl[lr_c][c0 - 1] + 0.25f * shl[lr_n][c0 - 1];
    float mb = 0.75f * shl[lr_c][c0    ] + 0.25f * shl[lr_n][c0    ];
    float mc = 0.75f * shl[lr_c][c0 + 1] + 0.25f * shl[lr_n][c0 + 1];
    float md = 0.75f * shl[lr_c][c0 + 2] + 0.25f * shl[lr_n][c0 + 2];

    float4 lu;
    lu.x = 0.75f * mb + 0.25f * ma;
    lu.y = 0.75f * mb + 0.25f * mc;
    lu.z = 0.75f * mc + 0.25f * mb;
    lu.w = 0.75f * mc + 0.25f * md;

    // ---- stores ----
    const size_t outM  = (size_t)T_LR * CCH * HH * WW;
    const size_t outLU = outM + (size_t)T_LR * HH * WW;
    const size_t oidx = (((size_t)i * CCH + ch) * HH + y) * WW + x;

    float4 fh;
    fh.x = lu.x + alpha * hp[0][0] + beta * hp[1][0];
    fh.y = lu.y + alpha * hp[0][1] + beta * hp[1][1];
    fh.z = lu.z + alpha * hp[0][2] + beta * hp[1][2];
    fh.w = lu.w + alpha * hp[0][3] + beta * hp[1][3];
    *(float4*)&out[oidx] = fh;
    *(float4*)&out[outLU + oidx] = lu;

    // ---- final_mask: only channel-0 blocks ----
    if (ch == 0) {
        int4 mf = *(const int4*)(hr_mask + ((size_t)f * HH + y) * WW + x);
        int4 ms = *(const int4*)(hr_mask + ((size_t)s * HH + y) * WW + x);
        const int* lm = lr_mask + ((size_t)i * H0 + jy) * W0;
        int gjx0 = x >> 1;
        int m0 = lm[gjx0], m1 = lm[gjx0 + 1];
        int nv = !valid;
        float4 mo;
        mo.x = (m0 | mf.x | ms.x | nv) ? 1.f : 0.f;
        mo.y = (m0 | mf.y | ms.y | nv) ? 1.f : 0.f;
        mo.z = (m1 | mf.z | ms.z | nv) ? 1.f : 0.f;
        mo.w = (m1 | mf.w | ms.w | nv) ? 1.f : 0.f;
        *(float4*)&out[outM + ((size_t)i * HH + y) * WW + x] = mo;
    }
}

extern "C" void kernel_launch(void* const* d_in, const int* in_sizes, int n_in,
                              void* d_out, int out_size, void* d_ws, size_t ws_size,
                              hipStream_t stream) {
    const float* lr_data = (const float*)d_in[0];
    const float* hr_data = (const float*)d_in[1];
    const int* lr_doy    = (const int*)d_in[2];
    const int* hr_doy    = (const int*)d_in[3];
    const int* lr_mask   = (const int*)d_in[4];
    const int* hr_mask   = (const int*)d_in[5];
    float* out = (float*)d_out;
    float* ws  = (float*)d_ws;
    int* wsi   = (int*)d_ws;

    // PSF weights (numpy-matching, computed in double)
    double sigma = sqrt(-2.0 * log(0.4)) / M_PI;
    double e1 = exp(-1.0 / (2.0 * sigma * sigma));
    double e2 = exp(-2.0 / (2.0 * sigma * sigma));
    double ssum = 1.0 + 4.0 * e1 + 4.0 * e2;
    float wc = (float)(1.0 / ssum);
    float we = (float)(e1 / ssum);
    float wk = (float)(e2 / ssum);

    zero_kernel<<<1, 64, 0, stream>>>(wsi);
    rate_kernel<<<T_HR * 8, 256, 0, stream>>>(hr_mask, wsi);
    select_kernel<<<1, 64, 0, stream>>>(lr_doy, hr_doy, ws);

    dim3 grid(WW / 32, HH / 32, T_LR * CCH);
    fuse_kernel<<<grid, 256, 0, stream>>>(lr_data, hr_data, lr_mask, hr_mask,
                                          ws, out, wc, we, wk);
}

// Round 5
// 88.024 us; speedup vs baseline: 3.8216x; 1.5655x over previous
//
#include <hip/hip_runtime.h>
#include <math.h>

#define T_LR 20
#define T_HR 30
#define CCH  4
#define H0   256
#define W0   256
#define HH   512
#define WW   512
#define ABOVE 10000

typedef float f32x4 __attribute__((ext_vector_type(4)));

// ws layout (32-bit slots):
#define WS_FIDX  0    // 20 ints
#define WS_SIDX  32   // 20 ints
#define WS_ALPHA 64   // 20 floats
#define WS_BETA  96   // 20 floats
#define WS_VALID 128  // 20 ints
#define WS_CNT   160  // 240 ints (partial sums, 8 per frame)

// ---------------- Phase A1: per-HR-frame mask count (240 partial slots) ----------------
__global__ void rate_kernel(const int* __restrict__ hr_mask,
                            int* __restrict__ wsi) {
    int j = blockIdx.x >> 3;          // frame
    int slice = blockIdx.x & 7;       // 1/8 of frame
    const int elems = HH * WW / 8;    // 32768 ints per slice
    const uint4* p = (const uint4*)(hr_mask + (size_t)j * HH * WW + (size_t)slice * elems);
    int sum = 0;
    for (int e = threadIdx.x; e < elems / 4; e += blockDim.x) {
        uint4 v = p[e];
        sum += (int)(v.x + v.y + v.z + v.w);
    }
    for (int o = 32; o; o >>= 1) sum += __shfl_down(sum, o);
    __shared__ int ssum[4];
    if ((threadIdx.x & 63) == 0) ssum[threadIdx.x >> 6] = sum;
    __syncthreads();
    if (threadIdx.x == 0)
        wsi[WS_CNT + blockIdx.x] = ssum[0] + ssum[1] + ssum[2] + ssum[3];
}

// ---------------- Phase A2: first/second frame selection ----------------
__global__ void select_kernel(const int* __restrict__ lr_doy,
                              const int* __restrict__ hr_doy,
                              float* __restrict__ ws) {
    int i = threadIdx.x;
    if (i >= T_LR) return;
    const int* wsi_c = (const int*)ws;
    int doy = lr_doy[i];

    int fmin = ABOVE, fidx = 0;
    for (int j = 0; j < T_HR; j++) {
        int d = doy - hr_doy[j];
        if (d < 0) d = ABOVE;
        int cnt = 0;
        for (int k = 0; k < 8; k++) cnt += wsi_c[WS_CNT + 8 * j + k];
        float rate = (float)cnt / (float)(HH * WW);
        if (rate > 0.5f) d = ABOVE;
        if (d < fmin) { fmin = d; fidx = j; }   // first-occurrence argmin
    }
    int smin = ABOVE, sidx = 0;
    for (int j = 0; j < T_HR; j++) {
        int d = doy - hr_doy[j];
        if (d < 0) d = ABOVE;
        int cnt = 0;
        for (int k = 0; k < 8; k++) cnt += wsi_c[WS_CNT + 8 * j + k];
        float rate = (float)cnt / (float)(HH * WW);
        if (rate > 0.5f) d = ABOVE;
        if (j == fidx) d = ABOVE;
        if (d < smin) { smin = d; sidx = j; }
    }
    int valid = (fmin < ABOVE) && (smin < ABOVE);
    float fv = (float)hr_doy[fidx], sv = (float)hr_doy[sidx];
    float denom = sv - fv;

    int* wsi = (int*)ws;
    wsi[WS_FIDX + i] = fidx;
    wsi[WS_SIDX + i] = sidx;
    ws[WS_ALPHA + i] = (sv - (float)doy) / denom;   // weight on g1
    ws[WS_BETA + i]  = ((float)doy - fv) / denom;   // weight on g2
    wsi[WS_VALID + i] = valid;
}

// ---------------- Phase B: fused main kernel ----------------
// grid (16,16,80). XCD-chunk swizzle: each XCD owns 10 contiguous z-slices.
__launch_bounds__(256)
__global__ void fuse_kernel(const float* __restrict__ lr_data,
                            const float* __restrict__ hr_data,
                            const int* __restrict__ lr_mask,
                            const int* __restrict__ hr_mask,
                            const float* __restrict__ ws,
                            float* __restrict__ out,
                            float wc, float we, float wk) {
    // bijective XCD chunk swizzle (20480 blocks, 8 XCDs, lin%8 == XCD)
    const int lin = blockIdx.x + (blockIdx.y << 4) + (blockIdx.z << 8);
    const int q = lin >> 3;
    const int z = (lin & 7) * 10 + (q >> 8);   // z in [0,80)
    const int t = q & 255;                     // tile in [0,256)
    const int i  = z >> 2;
    const int ch = z & 3;
    const int x0 = (t & 15) * 32;
    const int y0 = (t >> 4) * 32;
    const int tid = threadIdx.x;

    const int* wsi = (const int*)ws;
    const int f       = wsi[WS_FIDX + i];
    const int s       = wsi[WS_SIDX + i];
    const float alpha = ws[WS_ALPHA + i];
    const float beta  = ws[WS_BETA + i];
    const int valid   = wsi[WS_VALID + i];

    __shared__ float sh[2][34][44];   // HR halo tiles (stride 44: no r/r+4 bank alias)
    __shared__ float shl[18][28];     // LR tile (clamped)

    const float* g0 = hr_data + ((size_t)f * CCH + ch) * HH * WW;
    const float* g1 = hr_data + ((size_t)s * CCH + ch) * HH * WW;

    // HR staging: 2 imgs x 34 rows x 10 float4 (cols start at x0-4)
    for (int e = tid; e < 2 * 340; e += 256) {
        int img = e >= 340;
        int e2 = e - img * 340;
        int r = e2 / 10, c4 = e2 - r * 10;
        int gy = y0 - 1 + r;
        int gx0 = x0 - 4 + c4 * 4;
        float4 v = make_float4(0.f, 0.f, 0.f, 0.f);
        if (gy >= 0 && gy < HH && gx0 >= 0 && gx0 < WW)   // gx0 mult of 4 -> whole f4 valid
            v = *(const float4*)((img ? g1 : g0) + (size_t)gy * WW + gx0);
        *(float4*)&sh[img][r][c4 * 4] = v;
    }

    // LR staging: 18 rows x 6 float4, clamp-to-edge applied here (cols start x0/2-4)
    const int ly0 = (y0 >> 1) - 1, lx0c = (x0 >> 1) - 4;
    const float* lp = lr_data + ((size_t)i * CCH + ch) * H0 * W0;
    if (tid < 18 * 6) {
        int r = tid / 6, c4 = tid - r * 6;
        int gy = min(max(ly0 + r, 0), H0 - 1);
        int gx0 = lx0c + c4 * 4;
        float4 v;
        if (gx0 >= 0 && gx0 + 3 < W0) {
            v = *(const float4*)(lp + (size_t)gy * W0 + gx0);
        } else {
            v.x = lp[(size_t)gy * W0 + min(max(gx0 + 0, 0), W0 - 1)];
            v.y = lp[(size_t)gy * W0 + min(max(gx0 + 1, 0), W0 - 1)];
            v.z = lp[(size_t)gy * W0 + min(max(gx0 + 2, 0), W0 - 1)];
            v.w = lp[(size_t)gy * W0 + min(max(gx0 + 3, 0), W0 - 1)];
        }
        *(float4*)&shl[r][c4 * 4] = v;
    }
    __syncthreads();

    const int ty = tid >> 3, tx4 = tid & 7;
    const int y = y0 + ty, x = x0 + tx4 * 4;
    const int c = tx4 * 4 + 4;        // HR LDS col of x

    // ---- HPF for both images, 4 outputs each ----
    float hp[2][4];
    #pragma unroll
    for (int img = 0; img < 2; img++) {
        float win[3][6];
        #pragma unroll
        for (int rr = 0; rr < 3; rr++) {
            const float* row = sh[img][ty + rr];
            float4 v  = *(const float4*)&row[c];
            float2 a2 = *(const float2*)&row[c - 2];   // pairs to ds_read2_b64
            float2 b2 = *(const float2*)&row[c + 4];
            win[rr][0] = a2.y;
            win[rr][1] = v.x; win[rr][2] = v.y; win[rr][3] = v.z; win[rr][4] = v.w;
            win[rr][5] = b2.x;
        }
        #pragma unroll
        for (int k = 0; k < 4; k++) {
            float center = win[1][k + 1];
            float low =
                wk * (win[0][k] + win[0][k + 2] + win[2][k] + win[2][k + 2]) +
                we * (win[0][k + 1] + win[2][k + 1] + win[1][k] + win[1][k + 2]) +
                wc * center;
            hp[img][k] = center - low;
        }
    }

    // ---- bilinear upsample (clamping folded into staging) ----
    const int jy = y >> 1;
    const int lr_c = jy - ly0;                           // 1..16
    const int lr_n = jy + ((y & 1) ? 1 : -1) - ly0;      // 0..17
    const int c0 = tx4 * 2 + 4;                          // LDS col of jx = x>>1

    float ma = 0.75f * shl[lr_c][c0 - 1] + 0.25f * shl[lr_n][c0 - 1];
    float mb = 0.75f * shl[lr_c][c0    ] + 0.25f * shl[lr_n][c0    ];
    float mc = 0.75f * shl[lr_c][c0 + 1] + 0.25f * shl[lr_n][c0 + 1];
    float md = 0.75f * shl[lr_c][c0 + 2] + 0.25f * shl[lr_n][c0 + 2];

    f32x4 lu;
    lu.x = 0.75f * mb + 0.25f * ma;
    lu.y = 0.75f * mb + 0.25f * mc;
    lu.z = 0.75f * mc + 0.25f * mb;
    lu.w = 0.75f * mc + 0.25f * md;

    // ---- stores (nontemporal: streaming, never re-read) ----
    const size_t outM  = (size_t)T_LR * CCH * HH * WW;
    const size_t outLU = outM + (size_t)T_LR * HH * WW;
    const size_t oidx = (((size_t)i * CCH + ch) * HH + y) * WW + x;

    f32x4 fh;
    fh.x = lu.x + alpha * hp[0][0] + beta * hp[1][0];
    fh.y = lu.y + alpha * hp[0][1] + beta * hp[1][1];
    fh.z = lu.z + alpha * hp[0][2] + beta * hp[1][2];
    fh.w = lu.w + alpha * hp[0][3] + beta * hp[1][3];
    __builtin_nontemporal_store(fh, (f32x4*)&out[oidx]);
    __builtin_nontemporal_store(lu, (f32x4*)&out[outLU + oidx]);

    // ---- final_mask: only channel-0 blocks ----
    if (ch == 0) {
        int4 mf = *(const int4*)(hr_mask + ((size_t)f * HH + y) * WW + x);
        int4 ms = *(const int4*)(hr_mask + ((size_t)s * HH + y) * WW + x);
        const int* lm = lr_mask + ((size_t)i * H0 + jy) * W0;
        int gjx0 = x >> 1;
        int m0 = lm[gjx0], m1 = lm[gjx0 + 1];
        int nv = !valid;
        f32x4 mo;
        mo.x = (m0 | mf.x | ms.x | nv) ? 1.f : 0.f;
        mo.y = (m0 | mf.y | ms.y | nv) ? 1.f : 0.f;
        mo.z = (m1 | mf.z | ms.z | nv) ? 1.f : 0.f;
        mo.w = (m1 | mf.w | ms.w | nv) ? 1.f : 0.f;
        __builtin_nontemporal_store(mo, (f32x4*)&out[outM + ((size_t)i * HH + y) * WW + x]);
    }
}

extern "C" void kernel_launch(void* const* d_in, const int* in_sizes, int n_in,
                              void* d_out, int out_size, void* d_ws, size_t ws_size,
                              hipStream_t stream) {
    const float* lr_data = (const float*)d_in[0];
    const float* hr_data = (const float*)d_in[1];
    const int* lr_doy    = (const int*)d_in[2];
    const int* hr_doy    = (const int*)d_in[3];
    const int* lr_mask   = (const int*)d_in[4];
    const int* hr_mask   = (const int*)d_in[5];
    float* out = (float*)d_out;
    float* ws  = (float*)d_ws;
    int* wsi   = (int*)d_ws;

    // PSF weights (numpy-matching, computed in double)
    double sigma = sqrt(-2.0 * log(0.4)) / M_PI;
    double e1 = exp(-1.0 / (2.0 * sigma * sigma));
    double e2 = exp(-2.0 / (2.0 * sigma * sigma));
    double ssum = 1.0 + 4.0 * e1 + 4.0 * e2;
    float wc = (float)(1.0 / ssum);
    float we = (float)(e1 / ssum);
    float wk = (float)(e2 / ssum);

    rate_kernel<<<T_HR * 8, 256, 0, stream>>>(hr_mask, wsi);
    select_kernel<<<1, 64, 0, stream>>>(lr_doy, hr_doy, ws);

    dim3 grid(WW / 32, HH / 32, T_LR * CCH);
    fuse_kernel<<<grid, 256, 0, stream>>>(lr_data, hr_data, lr_mask, hr_mask,
                                          ws, out, wc, we, wk);
}

// Round 6
// 80.024 us; speedup vs baseline: 4.2036x; 1.1000x over previous
//
#include <hip/hip_runtime.h>
#include <math.h>

#define T_LR 20
#define T_HR 30
#define CCH  4
#define H0   256
#define W0   256
#define HH   512
#define WW   512
#define ABOVE 10000

typedef float f32x4 __attribute__((ext_vector_type(4)));

// ws layout (32-bit slots):
#define WS_FIDX  0    // 20 ints
#define WS_SIDX  32   // 20 ints
#define WS_ALPHA 64   // 20 floats
#define WS_BETA  96   // 20 floats
#define WS_VALID 128  // 20 ints
#define WS_CNT   160  // 240 ints (partial sums, 8 per frame)

// ---------------- Phase A1: per-HR-frame mask count (240 partial slots) ----------------
__global__ void rate_kernel(const int* __restrict__ hr_mask,
                            int* __restrict__ wsi) {
    int j = blockIdx.x >> 3;          // frame
    int slice = blockIdx.x & 7;       // 1/8 of frame
    const int elems = HH * WW / 8;    // 32768 ints per slice
    const uint4* p = (const uint4*)(hr_mask + (size_t)j * HH * WW + (size_t)slice * elems);
    int sum = 0;
    for (int e = threadIdx.x; e < elems / 4; e += blockDim.x) {
        uint4 v = p[e];
        sum += (int)(v.x + v.y + v.z + v.w);
    }
    for (int o = 32; o; o >>= 1) sum += __shfl_down(sum, o);
    __shared__ int ssum[4];
    if ((threadIdx.x & 63) == 0) ssum[threadIdx.x >> 6] = sum;
    __syncthreads();
    if (threadIdx.x == 0)
        wsi[WS_CNT + blockIdx.x] = ssum[0] + ssum[1] + ssum[2] + ssum[3];
}

// ---------------- Phase A2: first/second frame selection ----------------
__global__ void select_kernel(const int* __restrict__ lr_doy,
                              const int* __restrict__ hr_doy,
                              float* __restrict__ ws) {
    int i = threadIdx.x;
    if (i >= T_LR) return;
    const int* wsi_c = (const int*)ws;
    int doy = lr_doy[i];

    int fmin = ABOVE, fidx = 0;
    for (int j = 0; j < T_HR; j++) {
        int d = doy - hr_doy[j];
        if (d < 0) d = ABOVE;
        int cnt = 0;
        for (int k = 0; k < 8; k++) cnt += wsi_c[WS_CNT + 8 * j + k];
        float rate = (float)cnt / (float)(HH * WW);
        if (rate > 0.5f) d = ABOVE;
        if (d < fmin) { fmin = d; fidx = j; }   // first-occurrence argmin
    }
    int smin = ABOVE, sidx = 0;
    for (int j = 0; j < T_HR; j++) {
        int d = doy - hr_doy[j];
        if (d < 0) d = ABOVE;
        int cnt = 0;
        for (int k = 0; k < 8; k++) cnt += wsi_c[WS_CNT + 8 * j + k];
        float rate = (float)cnt / (float)(HH * WW);
        if (rate > 0.5f) d = ABOVE;
        if (j == fidx) d = ABOVE;
        if (d < smin) { smin = d; sidx = j; }
    }
    int valid = (fmin < ABOVE) && (smin < ABOVE);
    float fv = (float)hr_doy[fidx], sv = (float)hr_doy[sidx];
    float denom = sv - fv;

    int* wsi = (int*)ws;
    wsi[WS_FIDX + i] = fidx;
    wsi[WS_SIDX + i] = sidx;
    ws[WS_ALPHA + i] = (sv - (float)doy) / denom;   // weight on g1
    ws[WS_BETA + i]  = ((float)doy - fv) / denom;   // weight on g2
    wsi[WS_VALID + i] = valid;
}

// ---------------- Phase B: fused main kernel (separable PSF) ----------------
// grid (16,16,80). XCD-chunk swizzle. 3x3 Gaussian = [ga,gb,ga] x [ga,gb,ga]:
// stage horizontal blur H in LDS; compute does vertical pass only (all LDS
// access = aligned b128, 8 lanes = 32 consecutive words = conflict-free).
__launch_bounds__(256)
__global__ void fuse_kernel(const float* __restrict__ lr_data,
                            const float* __restrict__ hr_data,
                            const int* __restrict__ lr_mask,
                            const int* __restrict__ hr_mask,
                            const float* __restrict__ ws,
                            float* __restrict__ out,
                            float ga, float gb) {
    // bijective XCD chunk swizzle (20480 blocks, 8 XCDs, lin%8 == XCD)
    const int lin = blockIdx.x + (blockIdx.y << 4) + (blockIdx.z << 8);
    const int q = lin >> 3;
    const int z = (lin & 7) * 10 + (q >> 8);   // z in [0,80)
    const int t = q & 255;                     // tile in [0,256)
    const int i  = z >> 2;
    const int ch = z & 3;
    const int x0 = (t & 15) * 32;
    const int y0 = (t >> 4) * 32;
    const int tid = threadIdx.x;

    const int* wsi = (const int*)ws;
    const int f       = wsi[WS_FIDX + i];
    const int s       = wsi[WS_SIDX + i];
    const float alpha = ws[WS_ALPHA + i];
    const float beta  = ws[WS_BETA + i];
    const int valid   = wsi[WS_VALID + i];

    __shared__ float Hs[2][34][36];   // horizontal-blurred HR rows (y0-1 .. y0+32)
    __shared__ float hxs[18][36];     // horizontally-interpolated LR at HR res (32 cols)

    const float* g0 = hr_data + ((size_t)f * CCH + ch) * HH * WW;
    const float* g1 = hr_data + ((size_t)s * CCH + ch) * HH * WW;

    // ---- stage H: 2 imgs x 34 rows x 8 quads ----
    for (int e = tid; e < 544; e += 256) {
        int img = e >= 272;
        int e2 = e - img * 272;
        int rr = e2 >> 3, tq = e2 & 7;
        int gy = y0 - 1 + rr;
        f32x4 H = {0.f, 0.f, 0.f, 0.f};
        if (gy >= 0 && gy < HH) {                        // zero-pad rows
            const float* gp = (img ? g1 : g0) + (size_t)gy * WW;
            int gx = x0 + tq * 4;
            f32x4 v = *(const f32x4*)(gp + gx);
            float xl = (gx > 0)       ? gp[gx - 1] : 0.f;  // zero-pad cols
            float xr = (gx + 4 < WW)  ? gp[gx + 4] : 0.f;
            H.x = ga * (xl  + v.y) + gb * v.x;
            H.y = ga * (v.x + v.z) + gb * v.y;
            H.z = ga * (v.y + v.w) + gb * v.z;
            H.w = ga * (v.z + xr ) + gb * v.w;
        }
        *(f32x4*)&Hs[img][rr][tq * 4] = H;
    }

    // ---- stage hx: 18 rows x 8 quads (clamp-to-edge bilinear, horizontal) ----
    const int ly0 = (y0 >> 1) - 1;
    if (tid < 144) {
        int r = tid >> 3, tq = tid & 7;
        int gy = min(max(ly0 + r, 0), H0 - 1);
        const float* lp = lr_data + ((size_t)i * CCH + ch) * H0 * W0 + (size_t)gy * W0;
        int J = (x0 >> 1) + tq * 2;
        float vm = lp[max(J - 1, 0)];
        float v0 = lp[J];
        float v1 = lp[J + 1];
        float v2 = lp[min(J + 2, W0 - 1)];
        f32x4 hx;
        hx.x = 0.75f * v0 + 0.25f * vm;
        hx.y = 0.75f * v0 + 0.25f * v1;
        hx.z = 0.75f * v1 + 0.25f * v0;
        hx.w = 0.75f * v1 + 0.25f * v2;
        *(f32x4*)&hxs[r][tq * 4] = hx;
    }
    __syncthreads();

    const int ty = tid >> 3, tx4 = tid & 7;
    const int y = y0 + ty, x = x0 + tx4 * 4;
    const int c = tx4 * 4;

    // ---- vertical PSF pass + center re-read (L1-hot) ----
    f32x4 hu0 = *(const f32x4*)&Hs[0][ty    ][c];
    f32x4 hm0 = *(const f32x4*)&Hs[0][ty + 1][c];
    f32x4 hd0 = *(const f32x4*)&Hs[0][ty + 2][c];
    f32x4 hu1 = *(const f32x4*)&Hs[1][ty    ][c];
    f32x4 hm1 = *(const f32x4*)&Hs[1][ty + 1][c];
    f32x4 hd1 = *(const f32x4*)&Hs[1][ty + 2][c];
    f32x4 xc0 = *(const f32x4*)(g0 + (size_t)y * WW + x);
    f32x4 xc1 = *(const f32x4*)(g1 + (size_t)y * WW + x);
    f32x4 hp0 = xc0 - (ga * (hu0 + hd0) + gb * hm0);
    f32x4 hp1 = xc1 - (ga * (hu1 + hd1) + gb * hm1);

    // ---- vertical bilinear ----
    const int jy = y >> 1;
    const int rc = jy - ly0;
    const int rn = jy + ((y & 1) ? 1 : -1) - ly0;
    f32x4 ha = *(const f32x4*)&hxs[rc][c];
    f32x4 hb = *(const f32x4*)&hxs[rn][c];
    f32x4 lu = 0.75f * ha + 0.25f * hb;

    // ---- stores (nontemporal streaming) ----
    const size_t outM  = (size_t)T_LR * CCH * HH * WW;
    const size_t outLU = outM + (size_t)T_LR * HH * WW;
    const size_t oidx = (((size_t)i * CCH + ch) * HH + y) * WW + x;

    f32x4 fh = lu + alpha * hp0 + beta * hp1;
    __builtin_nontemporal_store(fh, (f32x4*)&out[oidx]);
    __builtin_nontemporal_store(lu, (f32x4*)&out[outLU + oidx]);

    // ---- final_mask: only channel-0 blocks ----
    if (ch == 0) {
        int4 mf = *(const int4*)(hr_mask + ((size_t)f * HH + y) * WW + x);
        int4 ms = *(const int4*)(hr_mask + ((size_t)s * HH + y) * WW + x);
        const int* lm = lr_mask + ((size_t)i * H0 + jy) * W0;
        int gjx0 = x >> 1;
        int m0 = lm[gjx0], m1 = lm[gjx0 + 1];
        int nv = !valid;
        f32x4 mo;
        mo.x = (m0 | mf.x | ms.x | nv) ? 1.f : 0.f;
        mo.y = (m0 | mf.y | ms.y | nv) ? 1.f : 0.f;
        mo.z = (m1 | mf.z | ms.z | nv) ? 1.f : 0.f;
        mo.w = (m1 | mf.w | ms.w | nv) ? 1.f : 0.f;
        __builtin_nontemporal_store(mo, (f32x4*)&out[outM + ((size_t)i * HH + y) * WW + x]);
    }
}

extern "C" void kernel_launch(void* const* d_in, const int* in_sizes, int n_in,
                              void* d_out, int out_size, void* d_ws, size_t ws_size,
                              hipStream_t stream) {
    const float* lr_data = (const float*)d_in[0];
    const float* hr_data = (const float*)d_in[1];
    const int* lr_doy    = (const int*)d_in[2];
    const int* hr_doy    = (const int*)d_in[3];
    const int* lr_mask   = (const int*)d_in[4];
    const int* hr_mask   = (const int*)d_in[5];
    float* out = (float*)d_out;
    float* ws  = (float*)d_ws;
    int* wsi   = (int*)d_ws;

    // Separable PSF: k = [ga,gb,ga] (x) [ga,gb,ga], per-axis normalized.
    // e2 == e1^2 exactly, so (1+2e1)^2 == 1+4e1+4e2 == full kernel sum.
    double sigma = sqrt(-2.0 * log(0.4)) / M_PI;
    double e1 = exp(-1.0 / (2.0 * sigma * sigma));
    double axis_sum = 1.0 + 2.0 * e1;
    float ga = (float)(e1 / axis_sum);
    float gb = (float)(1.0 / axis_sum);

    rate_kernel<<<T_HR * 8, 256, 0, stream>>>(hr_mask, wsi);
    select_kernel<<<1, 64, 0, stream>>>(lr_doy, hr_doy, ws);

    dim3 grid(WW / 32, HH / 32, T_LR * CCH);
    fuse_kernel<<<grid, 256, 0, stream>>>(lr_data, hr_data, lr_mask, hr_mask,
                                          ws, out, ga, gb);
}